// Round 18
// baseline (1969.773 us; speedup 1.0000x reference)
//
#include <hip/hip_runtime.h>
#include <hip/hip_bf16.h>
#include <math.h>

#define D_MODEL 768
#define N_HEAD  12
#define HEAD    64
#define SEQ     1024
#define NLAYER  6
#define BATCH   4
#define NROWS   (BATCH*SEQ)   // 4096
#define VOCAB   50257
#define VPAD    50432         // 197*256
#define DFFN    3072
#define DQKV    2304

typedef __attribute__((ext_vector_type(8))) __bf16 bf16x8;
typedef __attribute__((ext_vector_type(4))) float f32x4;
typedef __attribute__((ext_vector_type(4))) unsigned short u16x4;
typedef __attribute__((ext_vector_type(8))) unsigned short u16x8;

__device__ inline unsigned short f2bf(float x) {
    __hip_bfloat16 h = __float2bfloat16(x);
    return *reinterpret_cast<unsigned short*>(&h);
}

// ---------------- fused embedding + layer-0 LN1 ----------------
__global__ __launch_bounds__(256)
void embed_ln_kernel(const int* __restrict__ idx, const float* __restrict__ tok,
                     const float* __restrict__ pos, const float* __restrict__ gw,
                     const float* __restrict__ bw, float* __restrict__ x,
                     unsigned short* __restrict__ hb) {
    int row = blockIdx.x;
    int t = idx[row];
    int s = row & (SEQ - 1);
    int tid = threadIdx.x;
    const float* tp = tok + (size_t)t * D_MODEL;
    const float* pp = pos + (size_t)s * D_MODEL;
    float v0 = tp[tid]       + pp[tid];
    float v1 = tp[tid + 256] + pp[tid + 256];
    float v2 = tp[tid + 512] + pp[tid + 512];
    float* xp = x + (size_t)row * D_MODEL;
    xp[tid] = v0; xp[tid + 256] = v1; xp[tid + 512] = v2;
    float sm  = v0 + v1 + v2;
    float sq = v0*v0 + v1*v1 + v2*v2;
    #pragma unroll
    for (int o = 1; o < 64; o <<= 1) { sm += __shfl_xor(sm, o); sq += __shfl_xor(sq, o); }
    __shared__ float red[8];
    int wave = tid >> 6;
    if ((tid & 63) == 0) { red[wave] = sm; red[4 + wave] = sq; }
    __syncthreads();
    sm = red[0] + red[1] + red[2] + red[3];
    sq = red[4] + red[5] + red[6] + red[7];
    float mean = sm * (1.0f / D_MODEL);
    float var  = sq * (1.0f / D_MODEL) - mean * mean;
    float rstd = rsqrtf(var + 1e-5f);
    unsigned short* op = hb + (size_t)row * D_MODEL;
    op[tid]       = f2bf((v0 - mean) * rstd * gw[tid]       + bw[tid]);
    op[tid + 256] = f2bf((v1 - mean) * rstd * gw[tid + 256] + bw[tid + 256]);
    op[tid + 512] = f2bf((v2 - mean) * rstd * gw[tid + 512] + bw[tid + 512]);
}

// ---------------- layernorm: fp32 in, bf16 out ----------------
__global__ __launch_bounds__(256)
void ln_kernel(const float* __restrict__ in, const float* __restrict__ gw,
               const float* __restrict__ bw, unsigned short* __restrict__ out) {
    int row = blockIdx.x;
    int tid = threadIdx.x;
    const float* x = in + (size_t)row * D_MODEL;
    float v0 = x[tid], v1 = x[tid + 256], v2 = x[tid + 512];
    float s  = v0 + v1 + v2;
    float sq = v0*v0 + v1*v1 + v2*v2;
    #pragma unroll
    for (int o = 1; o < 64; o <<= 1) { s += __shfl_xor(s, o); sq += __shfl_xor(sq, o); }
    __shared__ float red[8];
    int wave = tid >> 6;
    if ((tid & 63) == 0) { red[wave] = s; red[4 + wave] = sq; }
    __syncthreads();
    s  = red[0] + red[1] + red[2] + red[3];
    sq = red[4] + red[5] + red[6] + red[7];
    float mean = s * (1.0f / D_MODEL);
    float var  = sq * (1.0f / D_MODEL) - mean * mean;
    float rstd = rsqrtf(var + 1e-5f);
    unsigned short* op = out + (size_t)row * D_MODEL;
    op[tid]       = f2bf((v0 - mean) * rstd * gw[tid]       + bw[tid]);
    op[tid + 256] = f2bf((v1 - mean) * rstd * gw[tid + 256] + bw[tid + 256]);
    op[tid + 512] = f2bf((v2 - mean) * rstd * gw[tid + 512] + bw[tid + 512]);
}

// ---------------- weight conversion (vectorized) ----------------
template<int MODE>
__global__ __launch_bounds__(256)
void conv_transpose(const float* __restrict__ in, unsigned short* __restrict__ out,
                    int K, int N, size_t inLstride, size_t outLstride) {
    __shared__ float t[64][65];
    const int tid = threadIdx.x;
    const int n0 = blockIdx.x * 64, k0 = blockIdx.y * 64;
    const float* ip = in + blockIdx.z * inLstride;
    unsigned short* op = out + blockIdx.z * outLstride;
    {
        const int kk = tid >> 4, nq = tid & 15;
        #pragma unroll
        for (int p = 0; p < 4; ++p) {
            int k = kk + p * 16;
            float4 v;
            if (MODE == 0) v = *reinterpret_cast<const float4*>(&ip[(size_t)(k0 + k) * N + n0 + nq * 4]);
            else           v = *reinterpret_cast<const float4*>(&ip[((size_t)(n0 >> 6) * K + (k0 + k)) * 64 + nq * 4]);
            t[k][nq * 4 + 0] = v.x; t[k][nq * 4 + 1] = v.y;
            t[k][nq * 4 + 2] = v.z; t[k][nq * 4 + 3] = v.w;
        }
    }
    __syncthreads();
    {
        const int n = tid >> 2, kq = tid & 3;
        unsigned short buf[16];
        #pragma unroll
        for (int j = 0; j < 16; ++j) buf[j] = f2bf(t[kq * 16 + j][n]);
        unsigned short* dst = &op[(size_t)(n0 + n) * K + k0 + kq * 16];
        *reinterpret_cast<u16x8*>(dst)     = *reinterpret_cast<u16x8*>(&buf[0]);
        *reinterpret_cast<u16x8*>(dst + 8) = *reinterpret_cast<u16x8*>(&buf[8]);
    }
}

__global__ __launch_bounds__(256)
void conv_lm(const float* __restrict__ in, unsigned short* __restrict__ out) {
    const int nchunks = VPAD * D_MODEL / 4;
    const int vchunks = VOCAB * D_MODEL / 4;
    for (int i = blockIdx.x * 256 + threadIdx.x; i < nchunks; i += gridDim.x * 256) {
        u16x4 o;
        if (i < vchunks) {
            float4 v = reinterpret_cast<const float4*>(in)[i];
            o[0] = f2bf(v.x); o[1] = f2bf(v.y); o[2] = f2bf(v.z); o[3] = f2bf(v.w);
        } else { o[0] = 0; o[1] = 0; o[2] = 0; o[3] = 0; }
        reinterpret_cast<u16x4*>(out)[i] = o;
    }
}

__global__ __launch_bounds__(256)
void conv_bias(const float* __restrict__ bq, const float* __restrict__ bk,
               const float* __restrict__ bv, float* __restrict__ out) {
    int i = blockIdx.x * 256 + threadIdx.x;
    if (i >= NLAYER * DQKV) return;
    int l = i / DQKV, n = i % DQKV;
    float v;
    if (n < 768)        v = bq[l * 768 + n];
    else if (n < 1536)  v = bk[l * 768 + n - 768];
    else                v = bv[l * 768 + n - 1536];
    out[i] = v;
}

// ---------------- 256x256 bf16 MFMA GEMM (logits), 8-PHASE schedule ----------------
// T3+T4+T5: per phase {ds-read frag subtile | stage 1 half-tile | barrier |
// 16 MFMA (setprio) | counted vmcnt(8) | barrier}. Half-tile = K-slice (32 cols).
// LDS 128 KiB = [2 buf][A,B][2 slice][256 rows][4 chunks][8 bf16], chunk swizzle
// phys = lc ^ ((row>>1)&3) (2-way conflicts only, both-sides per rule #21).
// WAR-safety: region staged at the phase right after its last reader phase.
// Last iteration drains with vmcnt(0) (skipped stages break the count rule).
__global__ __launch_bounds__(512)
void gemm256_mfma(const unsigned short* __restrict__ A, const unsigned short* __restrict__ B,
                  float* __restrict__ C, int M, int N, int K) {
    __shared__ unsigned short smem[65536];   // 128 KiB
    const int nwg = gridDim.x;
    const int t0 = (blockIdx.x & 7) * (nwg >> 3) + (blockIdx.x >> 3);
    const int MT = M >> 8;
    const int NBX = nwg / MT;
    const int srsize = NBX * 8;
    const int sr = t0 / srsize;
    const int rem = t0 - sr * srsize;
    const int bx = rem >> 3;
    const int by = sr * 8 + (rem & 7);
    const int bm = by * 256, bn = bx * 256;
    const int tid = threadIdx.x;
    const int l = tid & 63, w = tid >> 6;
    const int wm = w >> 2, wn = w & 3;
    const int lr = l & 15, lc = l >> 4;
    f32x4 acc[8][4] = {};

    // stage one half-tile (16 KB): mat 0=A 1=B, slice S of tile -> buf tile&1
    auto stageHalf = [&](int tile, int mat, int S) {
        const unsigned short* G = mat ? B : A;
        const int gbase = mat ? bn : bm;
        unsigned short* dst = &smem[(tile & 1) * 32768 + mat * 16384 + S * 8192];
        const int k0 = (tile << 6) + S * 32;
        #pragma unroll
        for (int p = 0; p < 2; ++p) {
            int u = p * 512 + tid;
            int row = u >> 2, qp = u & 3;
            int ql = qp ^ ((row >> 1) & 3);
            const unsigned short* g = G + (size_t)(gbase + row) * K + k0 + ql * 8;
            __builtin_amdgcn_global_load_lds(
                (const __attribute__((address_space(1))) unsigned int*)g,
                (__attribute__((address_space(3))) unsigned int*)(&dst[u * 8]), 16, 0, 0);
        }
    };
    auto readA4 = [&](int buf, int S, int mh, bf16x8* af) {
        const unsigned short* Ab = &smem[buf * 32768 + S * 8192];
        #pragma unroll
        for (int mi = 0; mi < 4; ++mi) {
            int R = wm * 128 + mh * 64 + mi * 16 + lr;
            af[mi] = *reinterpret_cast<const bf16x8*>(&Ab[R * 32 + ((lc ^ ((R >> 1) & 3)) * 8)]);
        }
    };
    auto readB4 = [&](int buf, int S, bf16x8* bfr) {
        const unsigned short* Bb = &smem[buf * 32768 + 16384 + S * 8192];
        #pragma unroll
        for (int ni = 0; ni < 4; ++ni) {
            int R = wn * 64 + ni * 16 + lr;
            bfr[ni] = *reinterpret_cast<const bf16x8*>(&Bb[R * 32 + ((lc ^ ((R >> 1) & 3)) * 8)]);
        }
    };

    const int NT = K >> 6;                   // 12 (even)
    // prologue: tile0 fully + tile1 ks0
    stageHalf(0, 0, 0); stageHalf(0, 1, 0); stageHalf(0, 0, 1); stageHalf(0, 1, 1);
    stageHalf(1, 0, 0); stageHalf(1, 1, 0);
    asm volatile("s_waitcnt vmcnt(0)" ::: "memory");
    __builtin_amdgcn_s_barrier();

    for (int i = 0; i < (NT >> 1); ++i) {
        const int T0 = 2 * i, T1 = T0 + 1;
        const bool lastit = (T0 + 2 >= NT);
        bf16x8 af[4], bfr[4];

        auto mfma16 = [&](int mh) {
            __builtin_amdgcn_s_setprio(1);
            #pragma unroll
            for (int mi = 0; mi < 4; ++mi)
                #pragma unroll
                for (int ni = 0; ni < 4; ++ni)
                    acc[mh * 4 + mi][ni] = __builtin_amdgcn_mfma_f32_16x16x32_bf16(
                        bfr[ni], af[mi], acc[mh * 4 + mi][ni], 0, 0, 0);   // SWAPPED
            __builtin_amdgcn_s_setprio(0);
        };
        auto phend = [&]() {
            if (lastit) asm volatile("s_waitcnt vmcnt(0)" ::: "memory");
            else        asm volatile("s_waitcnt vmcnt(8)" ::: "memory");
            __builtin_amdgcn_s_barrier();
        };

        // ph1: T0 ks0 mh0 | stage A-ks1(T1)
        readB4(0, 0, bfr); readA4(0, 0, 0, af);
        stageHalf(T1, 0, 1);
        __builtin_amdgcn_s_barrier();
        mfma16(0); phend();
        // ph2: T0 ks0 mh1 | stage B-ks1(T1)
        readA4(0, 0, 1, af);
        stageHalf(T1, 1, 1);
        __builtin_amdgcn_s_barrier();
        mfma16(1); phend();
        // ph3: T0 ks1 mh0 | stage A-ks0(T0+2)
        readB4(0, 1, bfr); readA4(0, 1, 0, af);
        if (!lastit) stageHalf(T0 + 2, 0, 0);
        __builtin_amdgcn_s_barrier();
        mfma16(0); phend();
        // ph4: T0 ks1 mh1 | stage B-ks0(T0+2)
        readA4(0, 1, 1, af);
        if (!lastit) stageHalf(T0 + 2, 1, 0);
        __builtin_amdgcn_s_barrier();
        mfma16(1); phend();
        // ph5: T1 ks0 mh0 | stage A-ks1(T0+2)
        readB4(1, 0, bfr); readA4(1, 0, 0, af);
        if (!lastit) stageHalf(T0 + 2, 0, 1);
        __builtin_amdgcn_s_barrier();
        mfma16(0); phend();
        // ph6: T1 ks0 mh1 | stage B-ks1(T0+2)
        readA4(1, 0, 1, af);
        if (!lastit) stageHalf(T0 + 2, 1, 1);
        __builtin_amdgcn_s_barrier();
        mfma16(1); phend();
        // ph7: T1 ks1 mh0 | stage A-ks0(T1+2)
        readB4(1, 1, bfr); readA4(1, 1, 0, af);
        if (!lastit) stageHalf(T1 + 2, 0, 0);
        __builtin_amdgcn_s_barrier();
        mfma16(0); phend();
        // ph8: T1 ks1 mh1 | stage B-ks0(T1+2)
        readA4(1, 1, 1, af);
        if (!lastit) stageHalf(T1 + 2, 1, 0);
        __builtin_amdgcn_s_barrier();
        mfma16(1); phend();
    }

    // swapped C/D: row = ...+lr, cols = ...+lc*4 (+0..3)
    #pragma unroll
    for (int i = 0; i < 8; ++i) {
        const int row = bm + wm * 128 + i * 16 + lr;
        #pragma unroll
        for (int j = 0; j < 4; ++j) {
            const int colb = bn + wn * 64 + j * 16 + lc * 4;
            if (colb + 3 < N) {
                *reinterpret_cast<f32x4*>(&C[(size_t)row * N + colb]) = acc[i][j];
            } else {
                #pragma unroll
                for (int r = 0; r < 4; ++r)
                    if (colb + r < N) C[(size_t)row * N + colb + r] = acc[i][j][r];
            }
        }
    }
}

// ---------------- 64xBN bf16 MFMA GEMM (layer GEMMs) ----------------
// BM=64; BN=128 (48KB, 3/CU) or BN=64 (32KB, 5/CU). Swapped-operand MFMA,
// f32x4/u16x4 epilogue; r12 slab mapping.
template<int BN, int OUTF /*0=f32,1=bf16*/, bool GELU, bool RES>
__global__ __launch_bounds__(256)
void gemm_sched(const unsigned short* __restrict__ A, const unsigned short* __restrict__ B,
                const float* __restrict__ bias, const float* __restrict__ res,
                void* __restrict__ Cout, int M, int N, int K) {
    constexpr int ABUF = 64 * 64;
    constexpr int TBUF = (64 + BN) * 64;
    constexpr int NI = BN / 32;
    __shared__ unsigned short smem[2 * TBUF];
    const int nwg = gridDim.x;
    const int t0 = (blockIdx.x & 7) * (nwg >> 3) + (blockIdx.x >> 3);
    const int MT = M >> 6;
    const int NBX = nwg / MT;
    const int srsize = NBX * 8;
    const int sr = t0 / srsize;
    const int rem = t0 - sr * srsize;
    const int bx = rem >> 3;
    const int by = sr * 8 + (rem & 7);
    const int bm = by * 64, bn = bx * BN;
    const int tid = threadIdx.x;
    const int l = tid & 63, w = tid >> 6;
    const int wr = (w & 1) * 32;
    const int wc = (w >> 1) * (BN / 2);
    const int lr = l & 15, lc = l >> 4;
    f32x4 acc[2][NI] = {};

    auto stage = [&](int k0, int buf) {
        #pragma unroll
        for (int p = 0; p < 2; ++p) {
            int d16 = p * 256 + tid;
            int row = d16 >> 3, cph = d16 & 7;
            int clog = cph ^ (row & 7);
            const unsigned short* ga = A + (size_t)(bm + row) * K + k0 + clog * 8;
            __builtin_amdgcn_global_load_lds(
                (const __attribute__((address_space(1))) unsigned int*)ga,
                (__attribute__((address_space(3))) unsigned int*)(&smem[buf * TBUF + d16 * 8]), 16, 0, 0);
        }
        #pragma unroll
        for (int p = 0; p < BN / 32; ++p) {
            int d16 = p * 256 + tid;
            int row = d16 >> 3, cph = d16 & 7;
            int clog = cph ^ (row & 7);
            const unsigned short* gb = B + (size_t)(bn + row) * K + k0 + clog * 8;
            __builtin_amdgcn_global_load_lds(
                (const __attribute__((address_space(1))) unsigned int*)gb,
                (__attribute__((address_space(3))) unsigned int*)(&smem[buf * TBUF + ABUF + d16 * 8]), 16, 0, 0);
        }
    };

    auto compute = [&](int buf) {
        const unsigned short* Ab = &smem[buf * TBUF];
        const unsigned short* Bb = &smem[buf * TBUF + ABUF];
        #pragma unroll
        for (int ks = 0; ks < 2; ++ks) {
            bf16x8 af[2], bfr[NI];
            #pragma unroll
            for (int mi = 0; mi < 2; ++mi) {
                int row = wr + mi * 16 + lr;
                af[mi] = *reinterpret_cast<const bf16x8*>(
                    &Ab[row * 64 + (((ks * 4 + lc) ^ (row & 7)) * 8)]);
            }
            #pragma unroll
            for (int ni = 0; ni < NI; ++ni) {
                int col = wc + ni * 16 + lr;
                bfr[ni] = *reinterpret_cast<const bf16x8*>(
                    &Bb[col * 64 + (((ks * 4 + lc) ^ (col & 7)) * 8)]);
            }
            __builtin_amdgcn_s_setprio(1);
            #pragma unroll
            for (int mi = 0; mi < 2; ++mi)
                #pragma unroll
                for (int ni = 0; ni < NI; ++ni)
                    acc[mi][ni] = __builtin_amdgcn_mfma_f32_16x16x32_bf16(
                        bfr[ni], af[mi], acc[mi][ni], 0, 0, 0);   // SWAPPED
            __builtin_amdgcn_s_setprio(0);
        }
    };

    const int NT = K >> 6;
    stage(0, 0);
    asm volatile("s_waitcnt vmcnt(0)" ::: "memory");
    __builtin_amdgcn_s_barrier();
    for (int t = 0; t < NT; ++t) {
        const int cur = t & 1;
        if (t + 1 < NT) stage((t + 1) << 6, cur ^ 1);
        compute(cur);
        if (t + 1 < NT) {
            asm volatile("s_waitcnt vmcnt(0)" ::: "memory");
            __builtin_amdgcn_s_barrier();
        }
    }

    #pragma unroll
    for (int mi = 0; mi < 2; ++mi) {
        const int row = bm + wr + mi * 16 + lr;
        #pragma unroll
        for (int ni = 0; ni < NI; ++ni) {
            const int colb = bn + wc + ni * 16 + lc * 4;
            f32x4 v = acc[mi][ni];
            if (bias) v += *reinterpret_cast<const f32x4*>(&bias[colb]);
            if (GELU) {
                #pragma unroll
                for (int r = 0; r < 4; ++r)
                    v[r] = 0.5f * v[r] * (1.0f + erff(v[r] * 0.70710678118654752f));
            }
            if (RES) v += *reinterpret_cast<const f32x4*>(&res[(size_t)row * N + colb]);
            if (OUTF == 0) {
                *reinterpret_cast<f32x4*>(&((float*)Cout)[(size_t)row * N + colb]) = v;
            } else {
                u16x4 o;
                o[0] = f2bf(v[0]); o[1] = f2bf(v[1]); o[2] = f2bf(v[2]); o[3] = f2bf(v[3]);
                *reinterpret_cast<u16x4*>(&((unsigned short*)Cout)[(size_t)row * N + colb]) = o;
            }
        }
    }
}

// ---------------- bf16 MFMA causal flash attention ----------------
// 128 q-rows/block, 8 waves. Double-buffered K/V LDS, issue-early reg staging,
// ONE barrier per KV tile.
__global__ __launch_bounds__(512)
void attn_mfma(const unsigned short* __restrict__ qkv, unsigned short* __restrict__ ao) {
    const int qt = gridDim.x - 1 - blockIdx.x;   // heavy blocks first
    const int h = blockIdx.y, b = blockIdx.z;
    const int tid = threadIdx.x;
    const int w = tid >> 6, l = tid & 63;
    const int c = l & 15, g = l >> 4;

    __shared__ unsigned short Ks[2][32 * 64];
    __shared__ unsigned short Vt[2][64 * 40];
    __shared__ unsigned int   Ps[8][16 * 20];

    const unsigned short* base = qkv + (size_t)(b * SEQ) * DQKV + h * HEAD;
    const int q0 = qt * 128 + w * 16;

    bf16x8 qf[2];
    {
        const unsigned short* qp = base + (size_t)(q0 + c) * DQKV + g * 8;
        qf[0] = *reinterpret_cast<const bf16x8*>(qp);
        qf[1] = *reinterpret_cast<const bf16x8*>(qp + 32);
    }

    f32x4 o_acc[4] = {};
    float m_run[4]  = {-INFINITY, -INFINITY, -INFINITY, -INFINITY};
    float l_run[4]  = {0.f, 0.f, 0.f, 0.f};

    const int srow = tid >> 4, sch8 = tid & 15;
    const int scj = sch8 >> 1, sh = sch8 & 1;
    const int vd = tid & 63, vw = tid >> 6;

    u16x4 kreg;
    unsigned short vreg[4];
    auto loadKV = [&](int kt) {
        kreg = *reinterpret_cast<const u16x4*>(
            base + (size_t)(kt * 32 + srow) * DQKV + 768 + sch8 * 4);
        #pragma unroll
        for (int j = 0; j < 4; ++j)
            vreg[j] = base[(size_t)(kt * 32 + vw * 4 + j) * DQKV + 1536 + vd];
    };

    const int nkt = 4 * qt + 4;
    loadKV(0);
    for (int kt = 0; kt < nkt; ++kt) {
        const int bf = kt & 1;
        *reinterpret_cast<u16x4*>(&Ks[bf][srow * 64 + ((scj ^ (srow & 7)) * 8) + sh * 4]) = kreg;
        {
            uint2 pk;
            pk.x = vreg[0] | ((unsigned)vreg[1] << 16);
            pk.y = vreg[2] | ((unsigned)vreg[3] << 16);
            *reinterpret_cast<uint2*>(&Vt[bf][vd * 40 + vw * 4]) = pk;
        }
        __syncthreads();
        if (kt + 1 < nkt) loadKV(kt + 1);

        f32x4 s_acc[2] = {};
        #pragma unroll
        for (int t = 0; t < 2; ++t) {
            const int kr = t * 16 + c;
            #pragma unroll
            for (int ks = 0; ks < 2; ++ks) {
                bf16x8 kf = *reinterpret_cast<const bf16x8*>(
                    &Ks[bf][kr * 64 + (((ks * 4 + g) ^ (kr & 7)) * 8)]);
                s_acc[t] = __builtin_amdgcn_mfma_f32_16x16x32_bf16(qf[ks], kf, s_acc[t], 0, 0, 0);
            }
        }
        float sc[2][4];
        #pragma unroll
        for (int t = 0; t < 2; ++t) {
            const int kglob = kt * 32 + t * 16 + c;
            #pragma unroll
            for (int r = 0; r < 4; ++r) {
                float v = s_acc[t][r] * 0.125f;
                sc[t][r] = (kglob > q0 + g * 4 + r) ? -1e30f : v;
            }
        }
        float pout[2][4];
        #pragma unroll
        for (int r = 0; r < 4; ++r) {
            float tmax = fmaxf(sc[0][r], sc[1][r]);
            #pragma unroll
            for (int ms = 1; ms < 16; ms <<= 1) tmax = fmaxf(tmax, __shfl_xor(tmax, ms));
            float mnew = fmaxf(m_run[r], tmax);
            float alpha = __expf(m_run[r] - mnew);
            float p0 = __expf(sc[0][r] - mnew);
            float p1 = __expf(sc[1][r] - mnew);
            float psum = p0 + p1;
            #pragma unroll
            for (int ms = 1; ms < 16; ms <<= 1) psum += __shfl_xor(psum, ms);
            l_run[r] = l_run[r] * alpha + psum;
            m_run[r] = mnew;
            #pragma unroll
            for (int dt = 0; dt < 4; ++dt) o_acc[dt][r] *= alpha;
            pout[0][r] = p0; pout[1][r] = p1;
        }
        #pragma unroll
        for (int t = 0; t < 2; ++t) {
            #pragma unroll
            for (int r = 0; r < 4; ++r) {
                int my = f2bf(pout[t][r]);
                int part = __shfl_xor(my, 1);
                unsigned int word = (c & 1) ? ((unsigned)(part & 0xffff) | ((unsigned)my << 16))
                                            : ((unsigned)(my & 0xffff) | ((unsigned)part << 16));
                Ps[w][(g * 4 + r) * 20 + t * 8 + (c >> 1)] = word;
            }
        }
        uint4 praw = *reinterpret_cast<const uint4*>(&Ps[w][c * 20 + g * 4]);
        bf16x8 pf = *reinterpret_cast<const bf16x8*>(&praw);
        #pragma unroll
        for (int dt = 0; dt < 4; ++dt) {
            bf16x8 vf = *reinterpret_cast<const bf16x8*>(&Vt[bf][(dt * 16 + c) * 40 + g * 8]);
            o_acc[dt] = __builtin_amdgcn_mfma_f32_16x16x32_bf16(pf, vf, o_acc[dt], 0, 0, 0);
        }
    }

    float inv[4];
    #pragma unroll
    for (int r = 0; r < 4; ++r) inv[r] = 1.0f / l_run[r];
    #pragma unroll
    for (int r = 0; r < 4; ++r) {
        unsigned short* op = ao + (size_t)(b * SEQ + q0 + g * 4 + r) * D_MODEL + h * HEAD + c;
        #pragma unroll
        for (int dt = 0; dt < 4; ++dt)
            op[dt * 16] = f2bf(o_acc[dt][r] * inv[r]);
    }
}

extern "C" void kernel_launch(void* const* d_in, const int* in_sizes, int n_in,
                              void* d_out, int out_size, void* d_ws, size_t ws_size,
                              hipStream_t stream) {
    const int*   idx     = (const int*)  d_in[0];
    const float* tok_emb = (const float*)d_in[1];
    const float* pos_emb = (const float*)d_in[2];
    const float* Wq      = (const float*)d_in[3];
    const float* bq      = (const float*)d_in[4];
    const float* Wk      = (const float*)d_in[5];
    const float* bk      = (const float*)d_in[6];
    const float* Wv      = (const float*)d_in[7];
    const float* bv      = (const float*)d_in[8];
    const float* Wproj   = (const float*)d_in[9];
    const float* bproj   = (const float*)d_in[10];
    const float* ln1g    = (const float*)d_in[11];
    const float* ln1b    = (const float*)d_in[12];
    const float* ln2g    = (const float*)d_in[13];
    const float* ln2b    = (const float*)d_in[14];
    const float* Wf1     = (const float*)d_in[15];
    const float* bf1     = (const float*)d_in[16];
    const float* Wf2     = (const float*)d_in[17];
    const float* bf2     = (const float*)d_in[18];
    const float* lnfg    = (const float*)d_in[19];
    const float* lnfb    = (const float*)d_in[20];
    const float* Wlm     = (const float*)d_in[21];
    float* outp = (float*)d_out;

    char* basep = (char*)d_ws;
    size_t off = 0;
    auto alloc = [&](size_t bytes) -> void* {
        void* p = basep + off;
        off = (off + bytes + 255) & ~(size_t)255;
        return p;
    };
    float*          x      = (float*)         alloc((size_t)NROWS * D_MODEL * 4);
    unsigned short* qkv    = (unsigned short*)alloc((size_t)NROWS * DQKV * 2);
    unsigned short* hb     = (unsigned short*)alloc((size_t)NROWS * D_MODEL * 2);
    unsigned short* ao     = (unsigned short*)alloc((size_t)NROWS * D_MODEL * 2);
    unsigned short* mid    = (unsigned short*)alloc((size_t)NROWS * DFFN * 2);
    unsigned short* Wqkvb  = (unsigned short*)alloc((size_t)NLAYER * DQKV * D_MODEL * 2);
    unsigned short* Wprojb = (unsigned short*)alloc((size_t)NLAYER * D_MODEL * D_MODEL * 2);
    unsigned short* Wf1b   = (unsigned short*)alloc((size_t)NLAYER * DFFN * D_MODEL * 2);
    unsigned short* Wf2b   = (unsigned short*)alloc((size_t)NLAYER * D_MODEL * DFFN * 2);
    unsigned short* Wlmb   = (unsigned short*)alloc((size_t)VPAD * D_MODEL * 2);
    float*          bqkv   = (float*)         alloc((size_t)NLAYER * DQKV * 4);

    dim3 blk(256);

    conv_lm<<<2048, blk, 0, stream>>>(Wlm, Wlmb);
    conv_transpose<1><<<dim3(12, 12, 6), blk, 0, stream>>>(Wq, Wqkvb,             768, 768,  (size_t)768*768,  (size_t)DQKV*768);
    conv_transpose<1><<<dim3(12, 12, 6), blk, 0, stream>>>(Wk, Wqkvb + 768*768,   768, 768,  (size_t)768*768,  (size_t)DQKV*768);
    conv_transpose<1><<<dim3(12, 12, 6), blk, 0, stream>>>(Wv, Wqkvb + 2*768*768, 768, 768,  (size_t)768*768,  (size_t)DQKV*768);
    conv_transpose<0><<<dim3(12, 12, 6), blk, 0, stream>>>(Wproj, Wprojb,         768, 768,  (size_t)768*768,  (size_t)768*768);
    conv_transpose<0><<<dim3(48, 12, 6), blk, 0, stream>>>(Wf1, Wf1b,             768, 3072, (size_t)768*3072, (size_t)3072*768);
    conv_transpose<0><<<dim3(12, 48, 6), blk, 0, stream>>>(Wf2, Wf2b,             3072, 768, (size_t)3072*768, (size_t)768*3072);
    conv_bias<<<(NLAYER * DQKV + 255) / 256, blk, 0, stream>>>(bq, bk, bv, bqkv);

    // fused embed + layer-0 LN1
    embed_ln_kernel<<<NROWS, blk, 0, stream>>>(idx, tok_emb, pos_emb, ln1g, ln1b, x, hb);

    dim3 gqkv(64 * 18);                  // BN=128, 1152 blocks
    dim3 g768s(64 * 12);                 // BN=64,  768 blocks (proj, FFN2)
    dim3 g3072(64 * 24);                 // BN=128, 1536 blocks (FFN1)
    dim3 ga(SEQ / 128, N_HEAD, BATCH);   // (8, 12, 4)

    for (int li = 0; li < NLAYER; ++li) {
        if (li > 0)
            ln_kernel<<<NROWS, blk, 0, stream>>>(x, ln1g + li * D_MODEL, ln1b + li * D_MODEL, hb);

        gemm_sched<128, 1, false, false><<<gqkv, blk, 0, stream>>>(
            hb, Wqkvb + (size_t)li * DQKV * D_MODEL, bqkv + li * DQKV, nullptr,
            qkv, NROWS, DQKV, D_MODEL);

        attn_mfma<<<ga, dim3(512), 0, stream>>>(qkv, ao);

        gemm_sched<64, 0, false, true><<<g768s, blk, 0, stream>>>(
            ao, Wprojb + (size_t)li * D_MODEL * D_MODEL, bproj + li * D_MODEL, x,
            x, NROWS, D_MODEL, D_MODEL);

        ln_kernel<<<NROWS, blk, 0, stream>>>(x, ln2g + li * D_MODEL, ln2b + li * D_MODEL, hb);

        gemm_sched<128, 1, true, false><<<g3072, blk, 0, stream>>>(
            hb, Wf1b + (size_t)li * DFFN * D_MODEL, bf1 + li * DFFN, nullptr,
            mid, NROWS, DFFN, D_MODEL);

        gemm_sched<64, 0, false, true><<<g768s, blk, 0, stream>>>(
            mid, Wf2b + (size_t)li * D_MODEL * DFFN, bf2 + li * D_MODEL, x,
            x, NROWS, D_MODEL, DFFN);
    }

    ln_kernel<<<NROWS, blk, 0, stream>>>(x, lnfg, lnfb, hb);

    dim3 gl((VPAD / 256) * (NROWS / 256));   // 197 * 16 = 3152 blocks
    gemm256_mfma<<<gl, dim3(512), 0, stream>>>(hb, Wlmb, outp, NROWS, VOCAB, D_MODEL);
}

// Round 19
// 1909.292 us; speedup vs baseline: 1.0317x; 1.0317x over previous
//
#include <hip/hip_runtime.h>
#include <hip/hip_bf16.h>
#include <math.h>

#define D_MODEL 768
#define N_HEAD  12
#define HEAD    64
#define SEQ     1024
#define NLAYER  6
#define BATCH   4
#define NROWS   (BATCH*SEQ)   // 4096
#define VOCAB   50257
#define VPAD    50432         // 197*256
#define DFFN    3072
#define DQKV    2304

typedef __attribute__((ext_vector_type(8))) __bf16 bf16x8;
typedef __attribute__((ext_vector_type(4))) float f32x4;
typedef __attribute__((ext_vector_type(4))) unsigned short u16x4;
typedef __attribute__((ext_vector_type(8))) unsigned short u16x8;

__device__ inline unsigned short f2bf(float x) {
    __hip_bfloat16 h = __float2bfloat16(x);
    return *reinterpret_cast<unsigned short*>(&h);
}

// ---------------- fused embedding + layer-0 LN1 ----------------
__global__ __launch_bounds__(256)
void embed_ln_kernel(const int* __restrict__ idx, const float* __restrict__ tok,
                     const float* __restrict__ pos, const float* __restrict__ gw,
                     const float* __restrict__ bw, float* __restrict__ x,
                     unsigned short* __restrict__ hb) {
    int row = blockIdx.x;
    int t = idx[row];
    int s = row & (SEQ - 1);
    int tid = threadIdx.x;
    const float* tp = tok + (size_t)t * D_MODEL;
    const float* pp = pos + (size_t)s * D_MODEL;
    float v0 = tp[tid]       + pp[tid];
    float v1 = tp[tid + 256] + pp[tid + 256];
    float v2 = tp[tid + 512] + pp[tid + 512];
    float* xp = x + (size_t)row * D_MODEL;
    xp[tid] = v0; xp[tid + 256] = v1; xp[tid + 512] = v2;
    float sm  = v0 + v1 + v2;
    float sq = v0*v0 + v1*v1 + v2*v2;
    #pragma unroll
    for (int o = 1; o < 64; o <<= 1) { sm += __shfl_xor(sm, o); sq += __shfl_xor(sq, o); }
    __shared__ float red[8];
    int wave = tid >> 6;
    if ((tid & 63) == 0) { red[wave] = sm; red[4 + wave] = sq; }
    __syncthreads();
    sm = red[0] + red[1] + red[2] + red[3];
    sq = red[4] + red[5] + red[6] + red[7];
    float mean = sm * (1.0f / D_MODEL);
    float var  = sq * (1.0f / D_MODEL) - mean * mean;
    float rstd = rsqrtf(var + 1e-5f);
    unsigned short* op = hb + (size_t)row * D_MODEL;
    op[tid]       = f2bf((v0 - mean) * rstd * gw[tid]       + bw[tid]);
    op[tid + 256] = f2bf((v1 - mean) * rstd * gw[tid + 256] + bw[tid + 256]);
    op[tid + 512] = f2bf((v2 - mean) * rstd * gw[tid + 512] + bw[tid + 512]);
}

// ---------------- layernorm: fp32 in, bf16 out ----------------
__global__ __launch_bounds__(256)
void ln_kernel(const float* __restrict__ in, const float* __restrict__ gw,
               const float* __restrict__ bw, unsigned short* __restrict__ out) {
    int row = blockIdx.x;
    int tid = threadIdx.x;
    const float* x = in + (size_t)row * D_MODEL;
    float v0 = x[tid], v1 = x[tid + 256], v2 = x[tid + 512];
    float s  = v0 + v1 + v2;
    float sq = v0*v0 + v1*v1 + v2*v2;
    #pragma unroll
    for (int o = 1; o < 64; o <<= 1) { s += __shfl_xor(s, o); sq += __shfl_xor(sq, o); }
    __shared__ float red[8];
    int wave = tid >> 6;
    if ((tid & 63) == 0) { red[wave] = s; red[4 + wave] = sq; }
    __syncthreads();
    s  = red[0] + red[1] + red[2] + red[3];
    sq = red[4] + red[5] + red[6] + red[7];
    float mean = s * (1.0f / D_MODEL);
    float var  = sq * (1.0f / D_MODEL) - mean * mean;
    float rstd = rsqrtf(var + 1e-5f);
    unsigned short* op = out + (size_t)row * D_MODEL;
    op[tid]       = f2bf((v0 - mean) * rstd * gw[tid]       + bw[tid]);
    op[tid + 256] = f2bf((v1 - mean) * rstd * gw[tid + 256] + bw[tid + 256]);
    op[tid + 512] = f2bf((v2 - mean) * rstd * gw[tid + 512] + bw[tid + 512]);
}

// ---------------- weight conversion (vectorized) ----------------
template<int MODE>
__global__ __launch_bounds__(256)
void conv_transpose(const float* __restrict__ in, unsigned short* __restrict__ out,
                    int K, int N, size_t inLstride, size_t outLstride) {
    __shared__ float t[64][65];
    const int tid = threadIdx.x;
    const int n0 = blockIdx.x * 64, k0 = blockIdx.y * 64;
    const float* ip = in + blockIdx.z * inLstride;
    unsigned short* op = out + blockIdx.z * outLstride;
    {
        const int kk = tid >> 4, nq = tid & 15;
        #pragma unroll
        for (int p = 0; p < 4; ++p) {
            int k = kk + p * 16;
            float4 v;
            if (MODE == 0) v = *reinterpret_cast<const float4*>(&ip[(size_t)(k0 + k) * N + n0 + nq * 4]);
            else           v = *reinterpret_cast<const float4*>(&ip[((size_t)(n0 >> 6) * K + (k0 + k)) * 64 + nq * 4]);
            t[k][nq * 4 + 0] = v.x; t[k][nq * 4 + 1] = v.y;
            t[k][nq * 4 + 2] = v.z; t[k][nq * 4 + 3] = v.w;
        }
    }
    __syncthreads();
    {
        const int n = tid >> 2, kq = tid & 3;
        unsigned short buf[16];
        #pragma unroll
        for (int j = 0; j < 16; ++j) buf[j] = f2bf(t[kq * 16 + j][n]);
        unsigned short* dst = &op[(size_t)(n0 + n) * K + k0 + kq * 16];
        *reinterpret_cast<u16x8*>(dst)     = *reinterpret_cast<u16x8*>(&buf[0]);
        *reinterpret_cast<u16x8*>(dst + 8) = *reinterpret_cast<u16x8*>(&buf[8]);
    }
}

// merged q/k/v transpose-convert: grid z = layer*3 + mat
__global__ __launch_bounds__(256)
void conv_qkv(const float* __restrict__ Wq, const float* __restrict__ Wk,
              const float* __restrict__ Wv, unsigned short* __restrict__ out) {
    __shared__ float t[64][65];
    const int tid = threadIdx.x;
    const int n0 = blockIdx.x * 64, k0 = blockIdx.y * 64;
    const int z = blockIdx.z, li = z / 3, m = z % 3;
    const int Kd = 768;
    const float* ip = (m == 0 ? Wq : (m == 1 ? Wk : Wv)) + (size_t)li * 768 * 768;
    unsigned short* op = out + (size_t)li * DQKV * 768 + (size_t)m * 768 * 768;
    {
        const int kk = tid >> 4, nq = tid & 15;
        #pragma unroll
        for (int p = 0; p < 4; ++p) {
            int k = kk + p * 16;
            float4 v = *reinterpret_cast<const float4*>(
                &ip[((size_t)(n0 >> 6) * Kd + (k0 + k)) * 64 + nq * 4]);
            t[k][nq * 4 + 0] = v.x; t[k][nq * 4 + 1] = v.y;
            t[k][nq * 4 + 2] = v.z; t[k][nq * 4 + 3] = v.w;
        }
    }
    __syncthreads();
    {
        const int n = tid >> 2, kq = tid & 3;
        unsigned short buf[16];
        #pragma unroll
        for (int j = 0; j < 16; ++j) buf[j] = f2bf(t[kq * 16 + j][n]);
        unsigned short* dst = &op[(size_t)(n0 + n) * Kd + k0 + kq * 16];
        *reinterpret_cast<u16x8*>(dst)     = *reinterpret_cast<u16x8*>(&buf[0]);
        *reinterpret_cast<u16x8*>(dst + 8) = *reinterpret_cast<u16x8*>(&buf[8]);
    }
}

__global__ __launch_bounds__(256)
void conv_lm(const float* __restrict__ in, unsigned short* __restrict__ out) {
    const int nchunks = VPAD * D_MODEL / 4;
    const int vchunks = VOCAB * D_MODEL / 4;
    for (int i = blockIdx.x * 256 + threadIdx.x; i < nchunks; i += gridDim.x * 256) {
        u16x4 o;
        if (i < vchunks) {
            float4 v = reinterpret_cast<const float4*>(in)[i];
            o[0] = f2bf(v.x); o[1] = f2bf(v.y); o[2] = f2bf(v.z); o[3] = f2bf(v.w);
        } else { o[0] = 0; o[1] = 0; o[2] = 0; o[3] = 0; }
        reinterpret_cast<u16x4*>(out)[i] = o;
    }
}

__global__ __launch_bounds__(256)
void conv_bias(const float* __restrict__ bq, const float* __restrict__ bk,
               const float* __restrict__ bv, float* __restrict__ out) {
    int i = blockIdx.x * 256 + threadIdx.x;
    if (i >= NLAYER * DQKV) return;
    int l = i / DQKV, n = i % DQKV;
    float v;
    if (n < 768)        v = bq[l * 768 + n];
    else if (n < 1536)  v = bk[l * 768 + n - 768];
    else                v = bv[l * 768 + n - 1536];
    out[i] = v;
}

// ---------------- 256x256 bf16 MFMA GEMM (logits), BK=64, 128 KiB ----------------
// r14-proven config: double-buffered issue-early staging, one vmcnt(0)+barrier
// per K-tile, r12 slab mapping, B-frag hoist, swapped operands, normal stores.
__global__ __launch_bounds__(512)
void gemm256_mfma(const unsigned short* __restrict__ A, const unsigned short* __restrict__ B,
                  float* __restrict__ C, int M, int N, int K) {
    __shared__ unsigned short smem[2 * 2 * 16384];   // 128 KiB
    const int nwg = gridDim.x;
    const int t0 = (blockIdx.x & 7) * (nwg >> 3) + (blockIdx.x >> 3);
    const int MT = M >> 8;
    const int NBX = nwg / MT;
    const int srsize = NBX * 8;
    const int sr = t0 / srsize;
    const int rem = t0 - sr * srsize;
    const int bx = rem >> 3;
    const int by = sr * 8 + (rem & 7);
    const int bm = by * 256, bn = bx * 256;
    const int tid = threadIdx.x;
    const int l = tid & 63, w = tid >> 6;
    const int wm = w >> 2, wn = w & 3;
    const int lr = l & 15, lc = l >> 4;
    f32x4 acc[8][4] = {};

    auto stage = [&](int k0, int buf) {
        #pragma unroll
        for (int p = 0; p < 4; ++p) {
            int d16 = p * 512 + tid;
            int row = d16 >> 3, cph = d16 & 7;
            int clog = cph ^ (row & 7);
            const unsigned short* ga = A + (size_t)(bm + row) * K + k0 + clog * 8;
            __builtin_amdgcn_global_load_lds(
                (const __attribute__((address_space(1))) unsigned int*)ga,
                (__attribute__((address_space(3))) unsigned int*)(&smem[buf * 32768 + d16 * 8]), 16, 0, 0);
        }
        #pragma unroll
        for (int p = 0; p < 4; ++p) {
            int d16 = p * 512 + tid;
            int row = d16 >> 3, cph = d16 & 7;
            int clog = cph ^ (row & 7);
            const unsigned short* gb = B + (size_t)(bn + row) * K + k0 + clog * 8;
            __builtin_amdgcn_global_load_lds(
                (const __attribute__((address_space(1))) unsigned int*)gb,
                (__attribute__((address_space(3))) unsigned int*)(&smem[buf * 32768 + 16384 + d16 * 8]), 16, 0, 0);
        }
    };

    auto compute = [&](int buf) {
        const unsigned short* Ab = &smem[buf * 32768];
        const unsigned short* Bb = &smem[buf * 32768 + 16384];
        bf16x8 bfr[2][4];   // B-frags read once per K-tile
        #pragma unroll
        for (int ks = 0; ks < 2; ++ks)
            #pragma unroll
            for (int j = 0; j < 4; ++j) {
                int col = wn * 64 + j * 16 + lr;
                bfr[ks][j] = *reinterpret_cast<const bf16x8*>(
                    &Bb[col * 64 + (((ks * 4 + lc) ^ (col & 7)) * 8)]);
            }
        #pragma unroll
        for (int qm = 0; qm < 2; ++qm) {
            bf16x8 af[2][4];
            #pragma unroll
            for (int ks = 0; ks < 2; ++ks)
                #pragma unroll
                for (int mi = 0; mi < 4; ++mi) {
                    int row = wm * 128 + qm * 64 + mi * 16 + lr;
                    af[ks][mi] = *reinterpret_cast<const bf16x8*>(
                        &Ab[row * 64 + (((ks * 4 + lc) ^ (row & 7)) * 8)]);
                }
            __builtin_amdgcn_s_setprio(1);
            #pragma unroll
            for (int ks = 0; ks < 2; ++ks)
                #pragma unroll
                for (int mi = 0; mi < 4; ++mi)
                    #pragma unroll
                    for (int j = 0; j < 4; ++j)
                        acc[qm * 4 + mi][j] = __builtin_amdgcn_mfma_f32_16x16x32_bf16(
                            bfr[ks][j], af[ks][mi], acc[qm * 4 + mi][j], 0, 0, 0);  // SWAPPED
            __builtin_amdgcn_s_setprio(0);
        }
    };

    const int NT = K >> 6;
    stage(0, 0);
    asm volatile("s_waitcnt vmcnt(0)" ::: "memory");
    __builtin_amdgcn_s_barrier();
    for (int t = 0; t < NT; ++t) {
        const int cur = t & 1;
        if (t + 1 < NT) stage((t + 1) << 6, cur ^ 1);
        compute(cur);
        if (t + 1 < NT) {
            asm volatile("s_waitcnt vmcnt(0)" ::: "memory");
            __builtin_amdgcn_s_barrier();
        }
    }

    // swapped C/D: row = ...+lr, cols = ...+lc*4 (+0..3)
    #pragma unroll
    for (int i = 0; i < 8; ++i) {
        const int row = bm + wm * 128 + i * 16 + lr;
        #pragma unroll
        for (int j = 0; j < 4; ++j) {
            const int colb = bn + wn * 64 + j * 16 + lc * 4;
            if (colb + 3 < N) {
                *reinterpret_cast<f32x4*>(&C[(size_t)row * N + colb]) = acc[i][j];
            } else {
                #pragma unroll
                for (int r = 0; r < 4; ++r)
                    if (colb + r < N) C[(size_t)row * N + colb + r] = acc[i][j][r];
            }
        }
    }
}

// ---------------- 64xBN bf16 MFMA GEMM (layer GEMMs) ----------------
// BM=64; BN=128 (48KB, 3/CU) or BN=64 (32KB, 5/CU). Swapped-operand MFMA,
// f32x4/u16x4 epilogue; r12 slab mapping.
template<int BN, int OUTF /*0=f32,1=bf16*/, bool GELU, bool RES>
__global__ __launch_bounds__(256)
void gemm_sched(const unsigned short* __restrict__ A, const unsigned short* __restrict__ B,
                const float* __restrict__ bias, const float* __restrict__ res,
                void* __restrict__ Cout, int M, int N, int K) {
    constexpr int ABUF = 64 * 64;
    constexpr int TBUF = (64 + BN) * 64;
    constexpr int NI = BN / 32;
    __shared__ unsigned short smem[2 * TBUF];
    const int nwg = gridDim.x;
    const int t0 = (blockIdx.x & 7) * (nwg >> 3) + (blockIdx.x >> 3);
    const int MT = M >> 6;
    const int NBX = nwg / MT;
    const int srsize = NBX * 8;
    const int sr = t0 / srsize;
    const int rem = t0 - sr * srsize;
    const int bx = rem >> 3;
    const int by = sr * 8 + (rem & 7);
    const int bm = by * 64, bn = bx * BN;
    const int tid = threadIdx.x;
    const int l = tid & 63, w = tid >> 6;
    const int wr = (w & 1) * 32;
    const int wc = (w >> 1) * (BN / 2);
    const int lr = l & 15, lc = l >> 4;
    f32x4 acc[2][NI] = {};

    auto stage = [&](int k0, int buf) {
        #pragma unroll
        for (int p = 0; p < 2; ++p) {
            int d16 = p * 256 + tid;
            int row = d16 >> 3, cph = d16 & 7;
            int clog = cph ^ (row & 7);
            const unsigned short* ga = A + (size_t)(bm + row) * K + k0 + clog * 8;
            __builtin_amdgcn_global_load_lds(
                (const __attribute__((address_space(1))) unsigned int*)ga,
                (__attribute__((address_space(3))) unsigned int*)(&smem[buf * TBUF + d16 * 8]), 16, 0, 0);
        }
        #pragma unroll
        for (int p = 0; p < BN / 32; ++p) {
            int d16 = p * 256 + tid;
            int row = d16 >> 3, cph = d16 & 7;
            int clog = cph ^ (row & 7);
            const unsigned short* gb = B + (size_t)(bn + row) * K + k0 + clog * 8;
            __builtin_amdgcn_global_load_lds(
                (const __attribute__((address_space(1))) unsigned int*)gb,
                (__attribute__((address_space(3))) unsigned int*)(&smem[buf * TBUF + ABUF + d16 * 8]), 16, 0, 0);
        }
    };

    auto compute = [&](int buf) {
        const unsigned short* Ab = &smem[buf * TBUF];
        const unsigned short* Bb = &smem[buf * TBUF + ABUF];
        #pragma unroll
        for (int ks = 0; ks < 2; ++ks) {
            bf16x8 af[2], bfr[NI];
            #pragma unroll
            for (int mi = 0; mi < 2; ++mi) {
                int row = wr + mi * 16 + lr;
                af[mi] = *reinterpret_cast<const bf16x8*>(
                    &Ab[row * 64 + (((ks * 4 + lc) ^ (row & 7)) * 8)]);
            }
            #pragma unroll
            for (int ni = 0; ni < NI; ++ni) {
                int col = wc + ni * 16 + lr;
                bfr[ni] = *reinterpret_cast<const bf16x8*>(
                    &Bb[col * 64 + (((ks * 4 + lc) ^ (col & 7)) * 8)]);
            }
            __builtin_amdgcn_s_setprio(1);
            #pragma unroll
            for (int mi = 0; mi < 2; ++mi)
                #pragma unroll
                for (int ni = 0; ni < NI; ++ni)
                    acc[mi][ni] = __builtin_amdgcn_mfma_f32_16x16x32_bf16(
                        bfr[ni], af[mi], acc[mi][ni], 0, 0, 0);   // SWAPPED
            __builtin_amdgcn_s_setprio(0);
        }
    };

    const int NT = K >> 6;
    stage(0, 0);
    asm volatile("s_waitcnt vmcnt(0)" ::: "memory");
    __builtin_amdgcn_s_barrier();
    for (int t = 0; t < NT; ++t) {
        const int cur = t & 1;
        if (t + 1 < NT) stage((t + 1) << 6, cur ^ 1);
        compute(cur);
        if (t + 1 < NT) {
            asm volatile("s_waitcnt vmcnt(0)" ::: "memory");
            __builtin_amdgcn_s_barrier();
        }
    }

    #pragma unroll
    for (int mi = 0; mi < 2; ++mi) {
        const int row = bm + wr + mi * 16 + lr;
        #pragma unroll
        for (int ni = 0; ni < NI; ++ni) {
            const int colb = bn + wc + ni * 16 + lc * 4;
            f32x4 v = acc[mi][ni];
            if (bias) v += *reinterpret_cast<const f32x4*>(&bias[colb]);
            if (GELU) {
                #pragma unroll
                for (int r = 0; r < 4; ++r)
                    v[r] = 0.5f * v[r] * (1.0f + erff(v[r] * 0.70710678118654752f));
            }
            if (RES) v += *reinterpret_cast<const f32x4*>(&res[(size_t)row * N + colb]);
            if (OUTF == 0) {
                *reinterpret_cast<f32x4*>(&((float*)Cout)[(size_t)row * N + colb]) = v;
            } else {
                u16x4 o;
                o[0] = f2bf(v[0]); o[1] = f2bf(v[1]); o[2] = f2bf(v[2]); o[3] = f2bf(v[3]);
                *reinterpret_cast<u16x4*>(&((unsigned short*)Cout)[(size_t)row * N + colb]) = o;
            }
        }
    }
}

// ---------------- bf16 MFMA causal flash attention ----------------
// 128 q-rows/block, 8 waves. Double-buffered K/V LDS, issue-early reg staging,
// ONE barrier per KV tile.
__global__ __launch_bounds__(512)
void attn_mfma(const unsigned short* __restrict__ qkv, unsigned short* __restrict__ ao) {
    const int qt = gridDim.x - 1 - blockIdx.x;   // heavy blocks first
    const int h = blockIdx.y, b = blockIdx.z;
    const int tid = threadIdx.x;
    const int w = tid >> 6, l = tid & 63;
    const int c = l & 15, g = l >> 4;

    __shared__ unsigned short Ks[2][32 * 64];
    __shared__ unsigned short Vt[2][64 * 40];
    __shared__ unsigned int   Ps[8][16 * 20];

    const unsigned short* base = qkv + (size_t)(b * SEQ) * DQKV + h * HEAD;
    const int q0 = qt * 128 + w * 16;

    bf16x8 qf[2];
    {
        const unsigned short* qp = base + (size_t)(q0 + c) * DQKV + g * 8;
        qf[0] = *reinterpret_cast<const bf16x8*>(qp);
        qf[1] = *reinterpret_cast<const bf16x8*>(qp + 32);
    }

    f32x4 o_acc[4] = {};
    float m_run[4]  = {-INFINITY, -INFINITY, -INFINITY, -INFINITY};
    float l_run[4]  = {0.f, 0.f, 0.f, 0.f};

    const int srow = tid >> 4, sch8 = tid & 15;
    const int scj = sch8 >> 1, sh = sch8 & 1;
    const int vd = tid & 63, vw = tid >> 6;

    u16x4 kreg;
    unsigned short vreg[4];
    auto loadKV = [&](int kt) {
        kreg = *reinterpret_cast<const u16x4*>(
            base + (size_t)(kt * 32 + srow) * DQKV + 768 + sch8 * 4);
        #pragma unroll
        for (int j = 0; j < 4; ++j)
            vreg[j] = base[(size_t)(kt * 32 + vw * 4 + j) * DQKV + 1536 + vd];
    };

    const int nkt = 4 * qt + 4;
    loadKV(0);
    for (int kt = 0; kt < nkt; ++kt) {
        const int bf = kt & 1;
        *reinterpret_cast<u16x4*>(&Ks[bf][srow * 64 + ((scj ^ (srow & 7)) * 8) + sh * 4]) = kreg;
        {
            uint2 pk;
            pk.x = vreg[0] | ((unsigned)vreg[1] << 16);
            pk.y = vreg[2] | ((unsigned)vreg[3] << 16);
            *reinterpret_cast<uint2*>(&Vt[bf][vd * 40 + vw * 4]) = pk;
        }
        __syncthreads();
        if (kt + 1 < nkt) loadKV(kt + 1);

        f32x4 s_acc[2] = {};
        #pragma unroll
        for (int t = 0; t < 2; ++t) {
            const int kr = t * 16 + c;
            #pragma unroll
            for (int ks = 0; ks < 2; ++ks) {
                bf16x8 kf = *reinterpret_cast<const bf16x8*>(
                    &Ks[bf][kr * 64 + (((ks * 4 + g) ^ (kr & 7)) * 8)]);
                s_acc[t] = __builtin_amdgcn_mfma_f32_16x16x32_bf16(qf[ks], kf, s_acc[t], 0, 0, 0);
            }
        }
        float sc[2][4];
        #pragma unroll
        for (int t = 0; t < 2; ++t) {
            const int kglob = kt * 32 + t * 16 + c;
            #pragma unroll
            for (int r = 0; r < 4; ++r) {
                float v = s_acc[t][r] * 0.125f;
                sc[t][r] = (kglob > q0 + g * 4 + r) ? -1e30f : v;
            }
        }
        float pout[2][4];
        #pragma unroll
        for (int r = 0; r < 4; ++r) {
            float tmax = fmaxf(sc[0][r], sc[1][r]);
            #pragma unroll
            for (int ms = 1; ms < 16; ms <<= 1) tmax = fmaxf(tmax, __shfl_xor(tmax, ms));
            float mnew = fmaxf(m_run[r], tmax);
            float alpha = __expf(m_run[r] - mnew);
            float p0 = __expf(sc[0][r] - mnew);
            float p1 = __expf(sc[1][r] - mnew);
            float psum = p0 + p1;
            #pragma unroll
            for (int ms = 1; ms < 16; ms <<= 1) psum += __shfl_xor(psum, ms);
            l_run[r] = l_run[r] * alpha + psum;
            m_run[r] = mnew;
            #pragma unroll
            for (int dt = 0; dt < 4; ++dt) o_acc[dt][r] *= alpha;
            pout[0][r] = p0; pout[1][r] = p1;
        }
        #pragma unroll
        for (int t = 0; t < 2; ++t) {
            #pragma unroll
            for (int r = 0; r < 4; ++r) {
                int my = f2bf(pout[t][r]);
                int part = __shfl_xor(my, 1);
                unsigned int word = (c & 1) ? ((unsigned)(part & 0xffff) | ((unsigned)my << 16))
                                            : ((unsigned)(my & 0xffff) | ((unsigned)part << 16));
                Ps[w][(g * 4 + r) * 20 + t * 8 + (c >> 1)] = word;
            }
        }
        uint4 praw = *reinterpret_cast<const uint4*>(&Ps[w][c * 20 + g * 4]);
        bf16x8 pf = *reinterpret_cast<const bf16x8*>(&praw);
        #pragma unroll
        for (int dt = 0; dt < 4; ++dt) {
            bf16x8 vf = *reinterpret_cast<const bf16x8*>(&Vt[bf][(dt * 16 + c) * 40 + g * 8]);
            o_acc[dt] = __builtin_amdgcn_mfma_f32_16x16x32_bf16(pf, vf, o_acc[dt], 0, 0, 0);
        }
    }

    float inv[4];
    #pragma unroll
    for (int r = 0; r < 4; ++r) inv[r] = 1.0f / l_run[r];
    #pragma unroll
    for (int r = 0; r < 4; ++r) {
        unsigned short* op = ao + (size_t)(b * SEQ + q0 + g * 4 + r) * D_MODEL + h * HEAD + c;
        #pragma unroll
        for (int dt = 0; dt < 4; ++dt)
            op[dt * 16] = f2bf(o_acc[dt][r] * inv[r]);
    }
}

extern "C" void kernel_launch(void* const* d_in, const int* in_sizes, int n_in,
                              void* d_out, int out_size, void* d_ws, size_t ws_size,
                              hipStream_t stream) {
    const int*   idx     = (const int*)  d_in[0];
    const float* tok_emb = (const float*)d_in[1];
    const float* pos_emb = (const float*)d_in[2];
    const float* Wq      = (const float*)d_in[3];
    const float* bq      = (const float*)d_in[4];
    const float* Wk      = (const float*)d_in[5];
    const float* bk      = (const float*)d_in[6];
    const float* Wv      = (const float*)d_in[7];
    const float* bv      = (const float*)d_in[8];
    const float* Wproj   = (const float*)d_in[9];
    const float* bproj   = (const float*)d_in[10];
    const float* ln1g    = (const float*)d_in[11];
    const float* ln1b    = (const float*)d_in[12];
    const float* ln2g    = (const float*)d_in[13];
    const float* ln2b    = (const float*)d_in[14];
    const float* Wf1     = (const float*)d_in[15];
    const float* bf1     = (const float*)d_in[16];
    const float* Wf2     = (const float*)d_in[17];
    const float* bf2     = (const float*)d_in[18];
    const float* lnfg    = (const float*)d_in[19];
    const float* lnfb    = (const float*)d_in[20];
    const float* Wlm     = (const float*)d_in[21];
    float* outp = (float*)d_out;

    char* basep = (char*)d_ws;
    size_t off = 0;
    auto alloc = [&](size_t bytes) -> void* {
        void* p = basep + off;
        off = (off + bytes + 255) & ~(size_t)255;
        return p;
    };
    float*          x      = (float*)         alloc((size_t)NROWS * D_MODEL * 4);
    unsigned short* qkv    = (unsigned short*)alloc((size_t)NROWS * DQKV * 2);
    unsigned short* hb     = (unsigned short*)alloc((size_t)NROWS * D_MODEL * 2);
    unsigned short* ao     = (unsigned short*)alloc((size_t)NROWS * D_MODEL * 2);
    unsigned short* mid    = (unsigned short*)alloc((size_t)NROWS * DFFN * 2);
    unsigned short* Wqkvb  = (unsigned short*)alloc((size_t)NLAYER * DQKV * D_MODEL * 2);
    unsigned short* Wprojb = (unsigned short*)alloc((size_t)NLAYER * D_MODEL * D_MODEL * 2);
    unsigned short* Wf1b   = (unsigned short*)alloc((size_t)NLAYER * DFFN * D_MODEL * 2);
    unsigned short* Wf2b   = (unsigned short*)alloc((size_t)NLAYER * D_MODEL * DFFN * 2);
    unsigned short* Wlmb   = (unsigned short*)alloc((size_t)VPAD * D_MODEL * 2);
    float*          bqkv   = (float*)         alloc((size_t)NLAYER * DQKV * 4);

    dim3 blk(256);

    conv_lm<<<2048, blk, 0, stream>>>(Wlm, Wlmb);
    conv_qkv<<<dim3(12, 12, 18), blk, 0, stream>>>(Wq, Wk, Wv, Wqkvb);
    conv_transpose<0><<<dim3(12, 12, 6), blk, 0, stream>>>(Wproj, Wprojb,  768, 768,  (size_t)768*768,  (size_t)768*768);
    conv_transpose<0><<<dim3(48, 12, 6), blk, 0, stream>>>(Wf1, Wf1b,      768, 3072, (size_t)768*3072, (size_t)3072*768);
    conv_transpose<0><<<dim3(12, 48, 6), blk, 0, stream>>>(Wf2, Wf2b,      3072, 768, (size_t)3072*768, (size_t)768*3072);
    conv_bias<<<(NLAYER * DQKV + 255) / 256, blk, 0, stream>>>(bq, bk, bv, bqkv);

    // fused embed + layer-0 LN1
    embed_ln_kernel<<<NROWS, blk, 0, stream>>>(idx, tok_emb, pos_emb, ln1g, ln1b, x, hb);

    dim3 gqkv(64 * 18);                  // BN=128, 1152 blocks
    dim3 g768s(64 * 12);                 // BN=64,  768 blocks (proj, FFN2)
    dim3 g3072(64 * 24);                 // BN=128, 1536 blocks (FFN1)
    dim3 ga(SEQ / 128, N_HEAD, BATCH);   // (8, 12, 4)

    for (int li = 0; li < NLAYER; ++li) {
        if (li > 0)
            ln_kernel<<<NROWS, blk, 0, stream>>>(x, ln1g + li * D_MODEL, ln1b + li * D_MODEL, hb);

        gemm_sched<128, 1, false, false><<<gqkv, blk, 0, stream>>>(
            hb, Wqkvb + (size_t)li * DQKV * D_MODEL, bqkv + li * DQKV, nullptr,
            qkv, NROWS, DQKV, D_MODEL);

        attn_mfma<<<ga, dim3(512), 0, stream>>>(qkv, ao);

        gemm_sched<64, 0, false, true><<<g768s, blk, 0, stream>>>(
            ao, Wprojb + (size_t)li * D_MODEL * D_MODEL, bproj + li * D_MODEL, x,
            x, NROWS, D_MODEL, D_MODEL);

        ln_kernel<<<NROWS, blk, 0, stream>>>(x, ln2g + li * D_MODEL, ln2b + li * D_MODEL, hb);

        gemm_sched<128, 1, true, false><<<g3072, blk, 0, stream>>>(
            hb, Wf1b + (size_t)li * DFFN * D_MODEL, bf1 + li * DFFN, nullptr,
            mid, NROWS, DFFN, D_MODEL);

        gemm_sched<64, 0, false, true><<<g768s, blk, 0, stream>>>(
            mid, Wf2b + (size_t)li * D_MODEL * DFFN, bf2 + li * D_MODEL, x,
            x, NROWS, D_MODEL, DFFN);
    }

    ln_kernel<<<NROWS, blk, 0, stream>>>(x, lnfg, lnfb, hb);

    dim3 gl((VPAD / 256) * (NROWS / 256));   // 197 * 16 = 3152 blocks
    gemm256_mfma<<<gl, dim3(512), 0, stream>>>(hb, Wlmb, outp, NROWS, VOCAB, D_MODEL);
}